// Round 3
// baseline (2989.797 us; speedup 1.0000x reference)
//
#include <hip/hip_runtime.h>
#include <hip/hip_bf16.h>

#define NN   40000
#define NE   160000
#define ETOT 200000   // NE + NN self loops
#define FIN  602
#define NH1  8
#define C1   256
#define F1   2048     // NH1*C1
#define C2   42
#define NEG  0.2f
#define NB   157      // ceil(NN/256)

typedef unsigned short u16;
typedef unsigned int   u32;

__device__ __forceinline__ float bfu(u16 v){ return __uint_as_float(((u32)v) << 16); }
__device__ __forceinline__ float bflo(u32 u){ return __uint_as_float(u << 16); }
__device__ __forceinline__ float bfhi(u32 u){ return __uint_as_float(u & 0xffff0000u); }
__device__ __forceinline__ u16 f2bf(float f){
  u32 u = __float_as_uint(f);
  u32 r = (u + 0x7fffu + ((u >> 16) & 1u)) >> 16;   // RNE
  return (u16)r;
}

// ================= dtype probe =================
// flags[0] = imode: 1 if edge_index is int64, 0 if int32
// flags[1] = fmode: 1 if float tensors are f32, 0 if bf16
__global__ void probe_k(const u32* __restrict__ xw, const int* __restrict__ ei,
                        int* __restrict__ flags) {
  if (threadIdx.x == 0) {
    int zc = 0;
    for (int k = 0; k < 64; ++k) zc += (ei[2*k + 1] == 0) ? 1 : 0;
    flags[0] = (zc == 64) ? 1 : 0;
    int inr = 0;
    for (int k = 0; k < 64; ++k) {
      u32 low = xw[k] & 0xffffu;            // bf16 world: an actual bf16 value; f32 world: mantissa bits
      int e = (int)((low >> 7) & 0xff);
      inr += (e >= 100 && e <= 140) ? 1 : 0;
    }
    flags[1] = (inr >= 32) ? 0 : 1;
  }
}

// ================= canonicalization =================
__global__ void cvt_bf16_k(const void* __restrict__ src, u16* __restrict__ dst, int n,
                           const int* __restrict__ flags) {
  int i = blockIdx.x * 256 + threadIdx.x;
  if (i >= n) return;
  dst[i] = flags[1] ? f2bf(((const float*)src)[i]) : ((const u16*)src)[i];
}
__global__ void cvt_f32_k(const void* __restrict__ src, float* __restrict__ dst, int n,
                          const int* __restrict__ flags) {
  int i = blockIdx.x * 256 + threadIdx.x;
  if (i >= n) return;
  dst[i] = flags[1] ? ((const float*)src)[i] : bfu(((const u16*)src)[i]);
}

// ================= CSR build =================
__device__ __forceinline__ void edge_sd(const int* __restrict__ ei, int e, int imode,
                                        int& s, int& d) {
  if (e < NE) {
    if (imode) { s = ei[2*e]; d = ei[2*(NE + e)]; }
    else       { s = ei[e];   d = ei[NE + e];     }
  } else { s = d = e - NE; }
}

__global__ void deg_k(const int* __restrict__ ei, int* __restrict__ deg,
                      const int* __restrict__ flags) {
  int e = blockIdx.x * 256 + threadIdx.x;
  if (e >= ETOT) return;
  int s, d; edge_sd(ei, e, flags[0], s, d);
  atomicAdd(&deg[d], 1);
}

__global__ __launch_bounds__(256) void scan1_k(const int* __restrict__ deg,
                                               int* __restrict__ tmp, int* __restrict__ bsum) {
  __shared__ int s[256];
  int b = blockIdx.x, t = threadIdx.x, i = b * 256 + t;
  int v = (i < NN) ? deg[i] : 0;
  s[t] = v; __syncthreads();
  for (int o = 1; o < 256; o <<= 1) {
    int u = (t >= o) ? s[t - o] : 0;
    __syncthreads(); s[t] += u; __syncthreads();
  }
  if (i < NN) tmp[i] = s[t];
  if (t == 255) bsum[b] = s[255];
}

__global__ __launch_bounds__(256) void scan2_k(int* __restrict__ bsum) {
  __shared__ int s[256];
  int t = threadIdx.x;
  int v = (t < NB) ? bsum[t] : 0;
  s[t] = v; __syncthreads();
  for (int o = 1; o < 256; o <<= 1) {
    int u = (t >= o) ? s[t - o] : 0;
    __syncthreads(); s[t] += u; __syncthreads();
  }
  if (t < NB) bsum[t] = s[t];
}

__global__ void scan3_k(const int* __restrict__ deg, const int* __restrict__ tmp,
                        const int* __restrict__ bsum, int* __restrict__ start, int* __restrict__ cur) {
  int i = blockIdx.x * 256 + threadIdx.x;
  if (i >= NN) return;
  int b = i >> 8;
  int off = b ? bsum[b - 1] : 0;
  int excl = tmp[i] - deg[i] + off;
  start[i] = excl; cur[i] = excl;
}

__global__ void fill_k(const int* __restrict__ ei, int* __restrict__ cur,
                       int* __restrict__ csr_src, int* __restrict__ csr_dst,
                       const int* __restrict__ flags) {
  int e = blockIdx.x * 256 + threadIdx.x;
  if (e >= ETOT) return;
  int s, d; edge_sd(ei, e, flags[0], s, d);
  int pos = atomicAdd(&cur[d], 1);
  csr_src[pos] = s; csr_dst[pos] = d;
}

// ================= GEMM1 (per head): h1h[N][256] = x[N][602] @ W1c[:, head*256 : +256]
__global__ __launch_bounds__(256) void gemm1h_k(const void* __restrict__ x,
                                                const u16* __restrict__ W,
                                                u16* __restrict__ h1h, int colBase,
                                                const int* __restrict__ flags) {
  __shared__ float As[16][72];   // [k][row], padded
  __shared__ float Bs[16][72];   // [k][col], padded
  const int fm = flags[1];
  const int t  = threadIdx.x;
  const int tx = t & 15, ty = t >> 4;
  const int m0 = blockIdx.y * 64, n0 = blockIdx.x * 64;
  const int ar = t >> 2;            // A row 0..63
  const int ak = (t & 3) * 4;       // A k 0,4,8,12
  const int br = t >> 4;            // B k-row 0..15
  const int bc = (t & 15) * 4;      // B col 0..60
  float acc[4][4] = {};
  for (int k0 = 0; k0 < FIN; k0 += 16) {
    float av[4] = {0.f, 0.f, 0.f, 0.f};
    if (k0 + 16 <= FIN) {
      if (fm) {
        // f32: row byte base = row*2408 (mod 8 == 0); offset mult of 16B -> float2 aligned
        const float* xp = (const float*)x + (size_t)(m0 + ar) * FIN + k0 + ak;
        float2 p0 = *reinterpret_cast<const float2*>(xp);
        float2 p1 = *reinterpret_cast<const float2*>(xp + 2);
        av[0] = p0.x; av[1] = p0.y; av[2] = p1.x; av[3] = p1.y;
      } else {
        // bf16: row byte base = row*1204 (mod 4 == 0); offset mult of 8B -> u32 aligned
        const u16* xp = (const u16*)x + (size_t)(m0 + ar) * FIN + k0 + ak;
        u32 p0 = *reinterpret_cast<const u32*>(xp);
        u32 p1 = *reinterpret_cast<const u32*>(xp + 2);
        av[0] = bflo(p0); av[1] = bfhi(p0); av[2] = bflo(p1); av[3] = bfhi(p1);
      }
    } else {
      for (int q = 0; q < 4; ++q) {
        int k = k0 + ak + q;
        if (k < FIN)
          av[q] = fm ? ((const float*)x)[(size_t)(m0 + ar) * FIN + k]
                     : bfu(((const u16*)x)[(size_t)(m0 + ar) * FIN + k]);
      }
    }
    As[ak + 0][ar] = av[0]; As[ak + 1][ar] = av[1];
    As[ak + 2][ar] = av[2]; As[ak + 3][ar] = av[3];

    float4 bv = make_float4(0.f, 0.f, 0.f, 0.f);
    if (k0 + br < FIN) {
      ushort4 u = *reinterpret_cast<const ushort4*>(W + (size_t)(k0 + br) * F1 + colBase + n0 + bc);
      bv = make_float4(bfu(u.x), bfu(u.y), bfu(u.z), bfu(u.w));
    }
    *reinterpret_cast<float4*>(&Bs[br][bc]) = bv;
    __syncthreads();

    const int kmax = (FIN - k0 >= 16) ? 16 : (FIN - k0);
    for (int kk = 0; kk < kmax; ++kk) {
      float4 a = *reinterpret_cast<const float4*>(&As[kk][ty * 4]);
      float4 b = *reinterpret_cast<const float4*>(&Bs[kk][tx * 4]);
      acc[0][0] += a.x * b.x; acc[0][1] += a.x * b.y; acc[0][2] += a.x * b.z; acc[0][3] += a.x * b.w;
      acc[1][0] += a.y * b.x; acc[1][1] += a.y * b.y; acc[1][2] += a.y * b.z; acc[1][3] += a.y * b.w;
      acc[2][0] += a.z * b.x; acc[2][1] += a.z * b.y; acc[2][2] += a.z * b.z; acc[2][3] += a.z * b.w;
      acc[3][0] += a.w * b.x; acc[3][1] += a.w * b.y; acc[3][2] += a.w * b.z; acc[3][3] += a.w * b.w;
    }
    __syncthreads();
  }
  #pragma unroll
  for (int i = 0; i < 4; ++i) {
    size_t base = (size_t)(m0 + ty * 4 + i) * C1 + n0 + tx * 4;
    ushort4 o;
    o.x = f2bf(acc[i][0]); o.y = f2bf(acc[i][1]); o.z = f2bf(acc[i][2]); o.w = f2bf(acc[i][3]);
    *reinterpret_cast<ushort4*>(h1h + base) = o;
  }
}

// ================= attention scalars (per head)
__global__ __launch_bounds__(64) void att1h_k(const u16* __restrict__ h1h,
                                              const float* __restrict__ as1, const float* __restrict__ ad1,
                                              float* __restrict__ a_s, float* __restrict__ a_d, int head) {
  int n = blockIdx.x, t = threadIdx.x;
  const u16* hp = h1h + (size_t)n * C1;
  const float* sp = as1 + head * C1;
  const float* dp = ad1 + head * C1;
  float ss = 0.f, sd = 0.f;
  #pragma unroll
  for (int c = t; c < C1; c += 64) {
    float hv = bfu(hp[c]);
    ss += hv * sp[c];
    sd += hv * dp[c];
  }
  #pragma unroll
  for (int o = 32; o > 0; o >>= 1) {
    ss += __shfl_down(ss, o, 64);
    sd += __shfl_down(sd, o, 64);
  }
  if (t == 0) { a_s[n] = ss; a_d[n] = sd; }
}

// per-CSR-position exp score (per head)
__global__ void exh_k(const int* __restrict__ csr_src, const int* __restrict__ csr_dst,
                      const float* __restrict__ a_s, const float* __restrict__ a_d,
                      float* __restrict__ ex) {
  int j = blockIdx.x * 256 + threadIdx.x;
  if (j >= ETOT) return;
  float v = a_s[csr_src[j]] + a_d[csr_dst[j]];
  v = v > 0.f ? v : NEG * v;
  ex[j] = expf(v);
}

// per-node gather aggregation (per head), fused bias+ReLU, writes y1 column block
__global__ __launch_bounds__(256) void gath1h_k(const int* __restrict__ start, const int* __restrict__ deg,
                                                const int* __restrict__ csr_src, const float* __restrict__ ex,
                                                const u16* __restrict__ h1h, const float* __restrict__ b1,
                                                u16* __restrict__ y1, int head) {
  int n = blockIdx.x, t = threadIdx.x;
  int s0 = start[n], cnt = deg[n];
  float acc = 0.f, den = 0.f;
  for (int j = s0; j < s0 + cnt; ++j) {
    int s = csr_src[j];
    float e = ex[j];
    den += e;
    acc += e * bfu(h1h[(size_t)s * C1 + t]);
  }
  float r = acc / (den + 1e-16f) + b1[head * C1 + t];
  y1[(size_t)n * F1 + head * C1 + t] = f2bf(fmaxf(r, 0.f));
}

// ================= GEMM2: h2[N][42] = y1[N][2048] @ W2c[2048][42]
__global__ __launch_bounds__(256) void gemm2_k(const u16* __restrict__ y1,
                                               const u16* __restrict__ W2,
                                               float* __restrict__ h2) {
  int gid = blockIdx.x * 256 + threadIdx.x;
  if (gid >= NN * C2) return;
  int n = gid / C2, c = gid - n * C2;
  const u16* yp = y1 + (size_t)n * F1;   // row stride 4096B; 16B-aligned uint4
  const u16* wp = W2 + c;
  float acc0 = 0.f, acc1 = 0.f;
  for (int k = 0; k < F1; k += 8) {
    uint4 u = *reinterpret_cast<const uint4*>(yp + k);
    acc0 += bflo(u.x) * bfu(wp[(k + 0) * C2]);
    acc1 += bfhi(u.x) * bfu(wp[(k + 1) * C2]);
    acc0 += bflo(u.y) * bfu(wp[(k + 2) * C2]);
    acc1 += bfhi(u.y) * bfu(wp[(k + 3) * C2]);
    acc0 += bflo(u.z) * bfu(wp[(k + 4) * C2]);
    acc1 += bfhi(u.z) * bfu(wp[(k + 5) * C2]);
    acc0 += bflo(u.w) * bfu(wp[(k + 6) * C2]);
    acc1 += bfhi(u.w) * bfu(wp[(k + 7) * C2]);
  }
  h2[gid] = acc0 + acc1;
}

// ================= attention scalars layer 2
__global__ __launch_bounds__(64) void att2_k(const float* __restrict__ h2,
                                             const float* __restrict__ as2, const float* __restrict__ ad2,
                                             float* __restrict__ a_s, float* __restrict__ a_d) {
  int n = blockIdx.x, t = threadIdx.x;
  float ss = 0.f, sd = 0.f;
  if (t < C2) {
    float v = h2[(size_t)n * C2 + t];
    ss = v * as2[t];
    sd = v * ad2[t];
  }
  #pragma unroll
  for (int o = 32; o > 0; o >>= 1) {
    ss += __shfl_down(ss, o, 64);
    sd += __shfl_down(sd, o, 64);
  }
  if (t == 0) { a_s[n] = ss; a_d[n] = sd; }
}

// ================= layer-2 gather + bias + log_softmax, dual-format output
__global__ __launch_bounds__(64) void gath2_k(const int* __restrict__ start, const int* __restrict__ deg,
                                              const int* __restrict__ csr_src,
                                              const float* __restrict__ a_s, const float* __restrict__ a_d,
                                              const float* __restrict__ h2, const float* __restrict__ b2,
                                              void* __restrict__ outv, const int* __restrict__ flags) {
  int n = blockIdx.x, t = threadIdx.x;
  int s0 = start[n], cnt = deg[n];
  float ad = a_d[n];
  float acc = 0.f, den = 0.f;
  for (int j = s0; j < s0 + cnt; ++j) {
    int s = csr_src[j];
    float v = a_s[s] + ad;
    v = v > 0.f ? v : NEG * v;
    float e = expf(v);
    den += e;
    if (t < C2) acc += e * h2[(size_t)s * C2 + t];
  }
  float raw = (t < C2) ? acc / (den + 1e-16f) + b2[t] : -1e30f;
  float m = raw;
  #pragma unroll
  for (int o = 32; o > 0; o >>= 1) m = fmaxf(m, __shfl_down(m, o, 64));
  m = __shfl(m, 0, 64);
  float e2 = (t < C2) ? expf(raw - m) : 0.f;
  float ssum = e2;
  #pragma unroll
  for (int o = 32; o > 0; o >>= 1) ssum += __shfl_down(ssum, o, 64);
  ssum = __shfl(ssum, 0, 64);
  if (t < C2) {
    float v = raw - m - logf(ssum);
    if (flags[1]) ((float*)outv)[(size_t)n * C2 + t] = v;
    else          ((u16*) outv)[(size_t)n * C2 + t] = f2bf(v);
  }
}

extern "C" void kernel_launch(void* const* d_in, const int* in_sizes, int n_in,
                              void* d_out, int out_size, void* d_ws, size_t ws_size,
                              hipStream_t stream) {
  const void* x   = d_in[0];
  const int*  ei  = (const int*)d_in[1];
  const void* W1  = d_in[2];
  const void* as1 = d_in[3];
  const void* ad1 = d_in[4];
  const void* b1  = d_in[5];
  const void* W2  = d_in[6];
  const void* as2 = d_in[7];
  const void* ad2 = d_in[8];
  const void* b2  = d_in[9];

  char* ws = (char*)d_ws;
  u16*   y1      = (u16*)  (ws);                  // 163,840,000
  u16*   h1h     = (u16*)  (ws + 163840000);      //  20,480,000
  float* h2      = (float*)(ws + 184320000);      //   6,720,000
  float* ex1     = (float*)(ws + 191040000);      //     800,000
  float* a_s1    = (float*)(ws + 191840000);      //     160,000
  float* a_d1    = (float*)(ws + 192000000);      //     160,000
  float* a_s2    = (float*)(ws + 192160000);      //     160,000
  float* a_d2    = (float*)(ws + 192320000);      //     160,000
  int*   deg     = (int*)  (ws + 192480000);      //     160,000
  int*   start   = (int*)  (ws + 192640000);      //     160,000
  int*   cur     = (int*)  (ws + 192800000);      //     160,000
  int*   tmp     = (int*)  (ws + 192960000);      //     160,000
  int*   csr_src = (int*)  (ws + 193120000);      //     800,000
  int*   csr_dst = (int*)  (ws + 193920000);      //     800,000
  int*   bsum    = (int*)  (ws + 194720000);      //       1,024
  u16*   W1c     = (u16*)  (ws + 194721024);      //   2,465,792
  u16*   W2c     = (u16*)  (ws + 197186816);      //     172,032
  float* as1c    = (float*)(ws + 197358848);      //       8,192
  float* ad1c    = (float*)(ws + 197367040);      //       8,192
  float* b1c     = (float*)(ws + 197375232);      //       8,192
  float* as2c    = (float*)(ws + 197383424);      //         256
  float* ad2c    = (float*)(ws + 197383680);      //         256
  float* b2c     = (float*)(ws + 197383936);      //         256
  int*   flags   = (int*)  (ws + 197384192);      //         256
  const size_t TOTAL = 197384448;
  if (ws_size < TOTAL) return;  // diagnostic: zeros out -> absmax == stub value 6.72

  hipMemsetAsync(deg, 0, NN * sizeof(int), stream);

  probe_k<<<1, 64, 0, stream>>>((const u32*)x, ei, flags);

  cvt_bf16_k<<<(FIN * F1 + 255) / 256, 256, 0, stream>>>(W1, W1c, FIN * F1, flags);
  cvt_bf16_k<<<(F1 * C2 + 255) / 256, 256, 0, stream>>>(W2, W2c, F1 * C2, flags);
  cvt_f32_k<<<(F1 + 255) / 256, 256, 0, stream>>>(as1, as1c, F1, flags);
  cvt_f32_k<<<(F1 + 255) / 256, 256, 0, stream>>>(ad1, ad1c, F1, flags);
  cvt_f32_k<<<(F1 + 255) / 256, 256, 0, stream>>>(b1, b1c, F1, flags);
  cvt_f32_k<<<1, 256, 0, stream>>>(as2, as2c, C2, flags);
  cvt_f32_k<<<1, 256, 0, stream>>>(ad2, ad2c, C2, flags);
  cvt_f32_k<<<1, 256, 0, stream>>>(b2, b2c, C2, flags);

  const int EB = (ETOT + 255) / 256;   // 782
  deg_k  <<<EB, 256, 0, stream>>>(ei, deg, flags);
  scan1_k<<<NB, 256, 0, stream>>>(deg, tmp, bsum);
  scan2_k<<<1, 256, 0, stream>>>(bsum);
  scan3_k<<<NB, 256, 0, stream>>>(deg, tmp, bsum, start, cur);
  fill_k <<<EB, 256, 0, stream>>>(ei, cur, csr_src, csr_dst, flags);

  dim3 g1(C1 / 64, NN / 64);  // (4, 625)
  for (int h = 0; h < NH1; ++h) {
    gemm1h_k<<<g1, 256, 0, stream>>>(x, W1c, h1h, h * C1, flags);
    att1h_k <<<NN, 64, 0, stream>>>(h1h, as1c, ad1c, a_s1, a_d1, h);
    exh_k   <<<EB, 256, 0, stream>>>(csr_src, csr_dst, a_s1, a_d1, ex1);
    gath1h_k<<<NN, 256, 0, stream>>>(start, deg, csr_src, ex1, h1h, b1c, y1, h);
  }

  gemm2_k<<<(NN * C2 + 255) / 256, 256, 0, stream>>>(y1, W2c, h2);
  att2_k <<<NN, 64, 0, stream>>>(h2, as2c, ad2c, a_s2, a_d2);
  gath2_k<<<NN, 64, 0, stream>>>(start, deg, csr_src, a_s2, a_d2, h2, b2c, d_out, flags);
}

// Round 4
// 906.747 us; speedup vs baseline: 3.2973x; 3.2973x over previous
//
#include <hip/hip_runtime.h>
#include <hip/hip_bf16.h>

#define NN   40000
#define NE   160000
#define ETOT 200000   // NE + NN self loops
#define FIN  602
#define NH1  8
#define C1   256
#define F1   2048     // NH1*C1
#define C2   42
#define NEG  0.2f
#define NB   157      // ceil(NN/256)
#define KP   608      // FIN padded to mult of 32

typedef unsigned short u16;
typedef unsigned int   u32;
typedef __bf16 bf16x8 __attribute__((ext_vector_type(8)));
typedef float  f32x4  __attribute__((ext_vector_type(4)));

__device__ __forceinline__ float bfu(u16 v){ return __uint_as_float(((u32)v) << 16); }
__device__ __forceinline__ float bflo(u32 u){ return __uint_as_float(u << 16); }
__device__ __forceinline__ float bfhi(u32 u){ return __uint_as_float(u & 0xffff0000u); }
__device__ __forceinline__ u16 f2bf(float f){
  u32 u = __float_as_uint(f);
  u32 r = (u + 0x7fffu + ((u >> 16) & 1u)) >> 16;   // RNE
  return (u16)r;
}

// ================= dtype probe =================
__global__ void probe_k(const u32* __restrict__ xw, const int* __restrict__ ei,
                        int* __restrict__ flags) {
  if (threadIdx.x == 0) {
    int zc = 0;
    for (int k = 0; k < 64; ++k) zc += (ei[2*k + 1] == 0) ? 1 : 0;
    flags[0] = (zc == 64) ? 1 : 0;
    int inr = 0;
    for (int k = 0; k < 64; ++k) {
      u32 low = xw[k] & 0xffffu;
      int e = (int)((low >> 7) & 0xff);
      inr += (e >= 100 && e <= 140) ? 1 : 0;
    }
    flags[1] = (inr >= 32) ? 0 : 1;
  }
}

__global__ void cvt_f32_k(const void* __restrict__ src, float* __restrict__ dst, int n,
                          const int* __restrict__ flags) {
  int i = blockIdx.x * 256 + threadIdx.x;
  if (i >= n) return;
  dst[i] = flags[1] ? ((const float*)src)[i] : bfu(((const u16*)src)[i]);
}

// W1t[n][k] = W1[k][n], k padded to 608 with zeros. bf16.
__global__ void w1t_k(const void* __restrict__ W1, u16* __restrict__ w1t,
                      const int* __restrict__ flags) {
  int n = blockIdx.x * 256 + threadIdx.x;
  int k = blockIdx.y;
  if (n >= F1) return;
  u16 v = 0;
  if (k < FIN) v = flags[1] ? f2bf(((const float*)W1)[(size_t)k * F1 + n])
                            : ((const u16*)W1)[(size_t)k * F1 + n];
  w1t[(size_t)n * KP + k] = v;
}

// W2p[k][c] padded cols 42->64 with zeros. bf16, k-major.
__global__ void w2p_k(const void* __restrict__ W2, u16* __restrict__ w2p,
                      const int* __restrict__ flags) {
  int i = blockIdx.x * 256 + threadIdx.x;
  if (i >= F1 * 64) return;
  int k = i >> 6, c = i & 63;
  u16 v = 0;
  if (c < C2) v = flags[1] ? f2bf(((const float*)W2)[(size_t)k * C2 + c])
                           : ((const u16*)W2)[(size_t)k * C2 + c];
  w2p[i] = v;
}

// ================= CSR build =================
__device__ __forceinline__ void edge_sd(const int* __restrict__ ei, int e, int imode,
                                        int& s, int& d) {
  if (e < NE) {
    if (imode) { s = ei[2*e]; d = ei[2*(NE + e)]; }
    else       { s = ei[e];   d = ei[NE + e];     }
  } else { s = d = e - NE; }
}

__global__ void deg_k(const int* __restrict__ ei, int* __restrict__ deg,
                      const int* __restrict__ flags) {
  int e = blockIdx.x * 256 + threadIdx.x;
  if (e >= ETOT) return;
  int s, d; edge_sd(ei, e, flags[0], s, d);
  atomicAdd(&deg[d], 1);
}

__global__ __launch_bounds__(256) void scan1_k(const int* __restrict__ deg,
                                               int* __restrict__ tmp, int* __restrict__ bsum) {
  __shared__ int s[256];
  int b = blockIdx.x, t = threadIdx.x, i = b * 256 + t;
  int v = (i < NN) ? deg[i] : 0;
  s[t] = v; __syncthreads();
  for (int o = 1; o < 256; o <<= 1) {
    int u = (t >= o) ? s[t - o] : 0;
    __syncthreads(); s[t] += u; __syncthreads();
  }
  if (i < NN) tmp[i] = s[t];
  if (t == 255) bsum[b] = s[255];
}

__global__ __launch_bounds__(256) void scan2_k(int* __restrict__ bsum) {
  __shared__ int s[256];
  int t = threadIdx.x;
  int v = (t < NB) ? bsum[t] : 0;
  s[t] = v; __syncthreads();
  for (int o = 1; o < 256; o <<= 1) {
    int u = (t >= o) ? s[t - o] : 0;
    __syncthreads(); s[t] += u; __syncthreads();
  }
  if (t < NB) bsum[t] = s[t];
}

__global__ void scan3_k(const int* __restrict__ deg, const int* __restrict__ tmp,
                        const int* __restrict__ bsum, int* __restrict__ start, int* __restrict__ cur) {
  int i = blockIdx.x * 256 + threadIdx.x;
  if (i >= NN) return;
  int b = i >> 8;
  int off = b ? bsum[b - 1] : 0;
  int excl = tmp[i] - deg[i] + off;
  start[i] = excl; cur[i] = excl;
}

__global__ void fill_k(const int* __restrict__ ei, int* __restrict__ cur,
                       int* __restrict__ csr_src, int* __restrict__ csr_dst,
                       const int* __restrict__ flags) {
  int e = blockIdx.x * 256 + threadIdx.x;
  if (e >= ETOT) return;
  int s, d; edge_sd(ei, e, flags[0], s, d);
  int pos = atomicAdd(&cur[d], 1);
  csr_src[pos] = s; csr_dst[pos] = d;
}

// ================= GEMM1 (MFMA): h1[40000][2048] = x[40000][602] @ W1[602][2048]
// 128x128 tile, BK=32, 4 waves 2x2, wave tile 64x64 (4x4 frags of 16x16x32)
__global__ __launch_bounds__(256) void gemm1m_k(const void* __restrict__ xv,
                                                const u16* __restrict__ w1t,
                                                u16* __restrict__ h1,
                                                const int* __restrict__ flags) {
  __shared__ u16 As[128][40];   // [row][k], +8 pad -> 80B row stride (2-way bank max)
  __shared__ u16 Bs[128][40];   // [n][k]
  const int fm = flags[1];
  const int t = threadIdx.x;
  const int lane = t & 63, wid = t >> 6;
  const int wr = wid >> 1, wc = wid & 1;
  const int m0 = blockIdx.y * 128, n0 = blockIdx.x * 128;
  const int l16 = lane & 15, lk = (lane >> 4) * 8;
  f32x4 acc[4][4];
  #pragma unroll
  for (int i = 0; i < 4; ++i)
    #pragma unroll
    for (int j = 0; j < 4; ++j) acc[i][j] = (f32x4){0.f, 0.f, 0.f, 0.f};

  const int arow = t >> 2;        // 0..63 (chunk rows; +64 on 2nd iter)
  const int akb  = (t & 3) * 8;   // k elem offset 0,8,16,24

  for (int k0 = 0; k0 < KP; k0 += 32) {
    #pragma unroll
    for (int i = 0; i < 2; ++i) {
      int row = arow + i * 64;
      int rg = m0 + row;
      u32 d0 = 0, d1 = 0, d2 = 0, d3 = 0;
      if (rg < NN) {
        if (k0 + 32 <= FIN) {
          if (fm) {
            const float* xp = (const float*)xv + (size_t)rg * FIN + k0 + akb;
            float2 p0 = *(const float2*)(xp);
            float2 p1 = *(const float2*)(xp + 2);
            float2 p2 = *(const float2*)(xp + 4);
            float2 p3 = *(const float2*)(xp + 6);
            d0 = (u32)f2bf(p0.x) | ((u32)f2bf(p0.y) << 16);
            d1 = (u32)f2bf(p1.x) | ((u32)f2bf(p1.y) << 16);
            d2 = (u32)f2bf(p2.x) | ((u32)f2bf(p2.y) << 16);
            d3 = (u32)f2bf(p3.x) | ((u32)f2bf(p3.y) << 16);
          } else {
            const u16* xp = (const u16*)xv + (size_t)rg * FIN + k0 + akb;
            d0 = *(const u32*)(xp);
            d1 = *(const u32*)(xp + 2);
            d2 = *(const u32*)(xp + 4);
            d3 = *(const u32*)(xp + 6);
          }
        } else {  // K tail tile (576..607), scalar with zero-fill
          u16 e[8];
          #pragma unroll
          for (int q = 0; q < 8; ++q) {
            int k = k0 + akb + q;
            e[q] = 0;
            if (k < FIN)
              e[q] = fm ? f2bf(((const float*)xv)[(size_t)rg * FIN + k])
                        : ((const u16*)xv)[(size_t)rg * FIN + k];
          }
          d0 = (u32)e[0] | ((u32)e[1] << 16);
          d1 = (u32)e[2] | ((u32)e[3] << 16);
          d2 = (u32)e[4] | ((u32)e[5] << 16);
          d3 = (u32)e[6] | ((u32)e[7] << 16);
        }
      }
      *(uint4*)&As[row][akb] = make_uint4(d0, d1, d2, d3);
      // B: W1t rows are zero-padded to KP, n range exact
      const u16* wp = w1t + (size_t)(n0 + row) * KP + k0 + akb;
      *(uint4*)&Bs[row][akb] = *(const uint4*)wp;
    }
    __syncthreads();
    bf16x8 bfr[4];
    #pragma unroll
    for (int ni = 0; ni < 4; ++ni)
      bfr[ni] = *(const bf16x8*)&Bs[wc * 64 + ni * 16 + l16][lk];
    #pragma unroll
    for (int mi = 0; mi < 4; ++mi) {
      bf16x8 af = *(const bf16x8*)&As[wr * 64 + mi * 16 + l16][lk];
      #pragma unroll
      for (int ni = 0; ni < 4; ++ni)
        acc[mi][ni] = __builtin_amdgcn_mfma_f32_16x16x32_bf16(af, bfr[ni], acc[mi][ni], 0, 0, 0);
    }
    __syncthreads();
  }
  const int lr4 = (lane >> 4) * 4;
  #pragma unroll
  for (int mi = 0; mi < 4; ++mi) {
    #pragma unroll
    for (int r = 0; r < 4; ++r) {
      int row = m0 + wr * 64 + mi * 16 + lr4 + r;
      if (row < NN) {
        #pragma unroll
        for (int ni = 0; ni < 4; ++ni) {
          int col = n0 + wc * 64 + ni * 16 + l16;
          h1[(size_t)row * F1 + col] = f2bf(acc[mi][ni][r]);
        }
      }
    }
  }
}

// ================= attention scalars, all 8 heads at once
__global__ __launch_bounds__(256) void att1_k(const u16* __restrict__ h1,
                                              const float* __restrict__ as1c, const float* __restrict__ ad1c,
                                              float* __restrict__ a_s, float* __restrict__ a_d) {
  int n = blockIdx.x, t = threadIdx.x;
  int h = t >> 5, l = t & 31;
  int base = h * C1 + l * 8;
  const u16* hp = h1 + (size_t)n * F1 + base;
  uint4 v = *(const uint4*)hp;
  u32 w[4] = {v.x, v.y, v.z, v.w};
  float ss = 0.f, sd = 0.f;
  #pragma unroll
  for (int p = 0; p < 4; ++p) {
    float e0 = bflo(w[p]), e1 = bfhi(w[p]);
    ss += e0 * as1c[base + 2*p] + e1 * as1c[base + 2*p + 1];
    sd += e0 * ad1c[base + 2*p] + e1 * ad1c[base + 2*p + 1];
  }
  #pragma unroll
  for (int o = 16; o > 0; o >>= 1) {
    ss += __shfl_down(ss, o, 32);
    sd += __shfl_down(sd, o, 32);
  }
  if (l == 0) { a_s[n * NH1 + h] = ss; a_d[n * NH1 + h] = sd; }
}

// per-CSR-position exp scores, all heads: ex1[j][h]
__global__ void ex1_k(const int* __restrict__ csr_src, const int* __restrict__ csr_dst,
                      const float* __restrict__ a_s, const float* __restrict__ a_d,
                      float* __restrict__ ex1) {
  int gid = blockIdx.x * 256 + threadIdx.x;
  if (gid >= ETOT * NH1) return;
  int j = gid >> 3, h = gid & 7;
  float v = a_s[csr_src[j] * NH1 + h] + a_d[csr_dst[j] * NH1 + h];
  v = v > 0.f ? v : NEG * v;
  ex1[gid] = expf(v);
}

// ================= fused: gather(all heads)+bias+ReLU -> LDS row -> @W2 -> h2[n][42]
// 4 nodes per block; W2p[2048][64] k-major padded.
__global__ __launch_bounds__(256) void gfuse_k(const int* __restrict__ start, const int* __restrict__ deg,
                                               const int* __restrict__ csr_src, const float* __restrict__ ex1,
                                               const u16* __restrict__ h1, const float* __restrict__ b1c,
                                               const u16* __restrict__ w2p, float* __restrict__ h2) {
  __shared__ u16 rowsL[4][F1];
  __shared__ float pb[4][4][64];
  int t = threadIdx.x;
  int nb = blockIdx.x * 4;
  // phase A: aggregate 4 nodes (thread t = channel t within each head)
  for (int i = 0; i < 4; ++i) {
    int n = nb + i;
    int s0 = start[n], cnt = deg[n];
    float acc[NH1], den[NH1];
    #pragma unroll
    for (int h = 0; h < NH1; ++h) { acc[h] = 0.f; den[h] = 0.f; }
    for (int j = s0; j < s0 + cnt; ++j) {
      int s = csr_src[j];
      const u16* hp = h1 + (size_t)s * F1 + t;
      const float* ep = ex1 + (size_t)j * NH1;
      #pragma unroll
      for (int h = 0; h < NH1; ++h) {
        float e = ep[h];
        den[h] += e;
        acc[h] += e * bfu(hp[h * C1]);
      }
    }
    #pragma unroll
    for (int h = 0; h < NH1; ++h) {
      float r = acc[h] / (den[h] + 1e-16f) + b1c[h * C1 + t];
      rowsL[i][h * C1 + t] = f2bf(fmaxf(r, 0.f));
    }
  }
  __syncthreads();
  // phase B: h2 = rows @ W2 (64 cols incl pad), wave g handles K quarter
  int c = t & 63, g = t >> 6;
  float f0 = 0.f, f1 = 0.f, f2 = 0.f, f3 = 0.f;
  for (int j = 0; j < 512; ++j) {
    int k = g * 512 + j;
    float w = bfu(w2p[(size_t)k * 64 + c]);
    f0 += w * bfu(rowsL[0][k]);
    f1 += w * bfu(rowsL[1][k]);
    f2 += w * bfu(rowsL[2][k]);
    f3 += w * bfu(rowsL[3][k]);
  }
  pb[0][g][c] = f0; pb[1][g][c] = f1; pb[2][g][c] = f2; pb[3][g][c] = f3;
  __syncthreads();
  int i2 = t >> 6, c2 = t & 63;
  if (c2 < C2) {
    float v = pb[i2][0][c2] + pb[i2][1][c2] + pb[i2][2][c2] + pb[i2][3][c2];
    h2[(size_t)(nb + i2) * C2 + c2] = v;
  }
}

// ================= attention scalars layer 2
__global__ __launch_bounds__(64) void att2_k(const float* __restrict__ h2,
                                             const float* __restrict__ as2, const float* __restrict__ ad2,
                                             float* __restrict__ a_s, float* __restrict__ a_d) {
  int n = blockIdx.x, t = threadIdx.x;
  float ss = 0.f, sd = 0.f;
  if (t < C2) {
    float v = h2[(size_t)n * C2 + t];
    ss = v * as2[t];
    sd = v * ad2[t];
  }
  #pragma unroll
  for (int o = 32; o > 0; o >>= 1) {
    ss += __shfl_down(ss, o, 64);
    sd += __shfl_down(sd, o, 64);
  }
  if (t == 0) { a_s[n] = ss; a_d[n] = sd; }
}

// ================= layer-2 gather + bias + log_softmax, dual-format output
__global__ __launch_bounds__(64) void gath2_k(const int* __restrict__ start, const int* __restrict__ deg,
                                              const int* __restrict__ csr_src,
                                              const float* __restrict__ a_s, const float* __restrict__ a_d,
                                              const float* __restrict__ h2, const float* __restrict__ b2,
                                              void* __restrict__ outv, const int* __restrict__ flags) {
  int n = blockIdx.x, t = threadIdx.x;
  int s0 = start[n], cnt = deg[n];
  float ad = a_d[n];
  float acc = 0.f, den = 0.f;
  for (int j = s0; j < s0 + cnt; ++j) {
    int s = csr_src[j];
    float v = a_s[s] + ad;
    v = v > 0.f ? v : NEG * v;
    float e = expf(v);
    den += e;
    if (t < C2) acc += e * h2[(size_t)s * C2 + t];
  }
  float raw = (t < C2) ? acc / (den + 1e-16f) + b2[t] : -1e30f;
  float m = raw;
  #pragma unroll
  for (int o = 32; o > 0; o >>= 1) m = fmaxf(m, __shfl_down(m, o, 64));
  m = __shfl(m, 0, 64);
  float e2 = (t < C2) ? expf(raw - m) : 0.f;
  float ssum = e2;
  #pragma unroll
  for (int o = 32; o > 0; o >>= 1) ssum += __shfl_down(ssum, o, 64);
  ssum = __shfl(ssum, 0, 64);
  if (t < C2) {
    float v = raw - m - logf(ssum);
    if (flags[1]) ((float*)outv)[(size_t)n * C2 + t] = v;
    else          ((u16*) outv)[(size_t)n * C2 + t] = f2bf(v);
  }
}

extern "C" void kernel_launch(void* const* d_in, const int* in_sizes, int n_in,
                              void* d_out, int out_size, void* d_ws, size_t ws_size,
                              hipStream_t stream) {
  const void* x   = d_in[0];
  const int*  ei  = (const int*)d_in[1];
  const void* W1  = d_in[2];
  const void* as1 = d_in[3];
  const void* ad1 = d_in[4];
  const void* b1  = d_in[5];
  const void* W2  = d_in[6];
  const void* as2 = d_in[7];
  const void* ad2 = d_in[8];
  const void* b2  = d_in[9];

  char* ws = (char*)d_ws;
  u16*   h1      = (u16*)  (ws);                  // 163,840,000
  float* ex1     = (float*)(ws + 163840000);      //   6,400,000
  float* h2      = (float*)(ws + 170240000);      //   6,720,000
  float* a_s1    = (float*)(ws + 176960000);      //   1,280,000
  float* a_d1    = (float*)(ws + 178240000);      //   1,280,000
  float* a_s2    = (float*)(ws + 179520000);      //     160,000
  float* a_d2    = (float*)(ws + 179680000);      //     160,000
  int*   deg     = (int*)  (ws + 179840000);      //     160,000
  int*   start   = (int*)  (ws + 180000000);      //     160,000
  int*   cur     = (int*)  (ws + 180160000);      //     160,000
  int*   tmp     = (int*)  (ws + 180320000);      //     160,000
  int*   csr_src = (int*)  (ws + 180480000);      //     800,000
  int*   csr_dst = (int*)  (ws + 181280000);      //     800,000
  int*   bsum    = (int*)  (ws + 182080000);      //       1,024
  u16*   w1t     = (u16*)  (ws + 182081024);      //   2,490,368
  u16*   w2p     = (u16*)  (ws + 184571392);      //     262,144
  float* as1c    = (float*)(ws + 184833536);      //       8,192
  float* ad1c    = (float*)(ws + 184841728);      //       8,192
  float* b1c     = (float*)(ws + 184849920);      //       8,192
  float* as2c    = (float*)(ws + 184858112);      //         256
  float* ad2c    = (float*)(ws + 184858368);      //         256
  float* b2c     = (float*)(ws + 184858624);      //         256
  int*   flags   = (int*)  (ws + 184858880);      //         256
  const size_t TOTAL = 184859136;
  if (ws_size < TOTAL) return;  // diagnostic: zeroed out -> clean absmax fail

  probe_k<<<1, 64, 0, stream>>>((const u32*)x, ei, flags);

  cvt_f32_k<<<(F1 + 255) / 256, 256, 0, stream>>>(as1, as1c, F1, flags);
  cvt_f32_k<<<(F1 + 255) / 256, 256, 0, stream>>>(ad1, ad1c, F1, flags);
  cvt_f32_k<<<(F1 + 255) / 256, 256, 0, stream>>>(b1, b1c, F1, flags);
  cvt_f32_k<<<1, 256, 0, stream>>>(as2, as2c, C2, flags);
  cvt_f32_k<<<1, 256, 0, stream>>>(ad2, ad2c, C2, flags);
  cvt_f32_k<<<1, 256, 0, stream>>>(b2, b2c, C2, flags);
  w1t_k<<<dim3(8, KP), 256, 0, stream>>>(W1, w1t, flags);
  w2p_k<<<(F1 * 64 + 255) / 256, 256, 0, stream>>>(W2, w2p, flags);

  hipMemsetAsync(deg, 0, NN * sizeof(int), stream);
  const int EB = (ETOT + 255) / 256;
  deg_k  <<<EB, 256, 0, stream>>>(ei, deg, flags);
  scan1_k<<<NB, 256, 0, stream>>>(deg, tmp, bsum);
  scan2_k<<<1, 256, 0, stream>>>(bsum);
  scan3_k<<<NB, 256, 0, stream>>>(deg, tmp, bsum, start, cur);
  fill_k <<<EB, 256, 0, stream>>>(ei, cur, csr_src, csr_dst, flags);

  gemm1m_k<<<dim3(16, 313), 256, 0, stream>>>(x, w1t, h1, flags);
  att1_k<<<NN, 256, 0, stream>>>(h1, as1c, ad1c, a_s1, a_d1);
  ex1_k<<<(ETOT * NH1 + 255) / 256, 256, 0, stream>>>(csr_src, csr_dst, a_s1, a_d1, ex1);
  gfuse_k<<<NN / 4, 256, 0, stream>>>(start, deg, csr_src, ex1, h1, b1c, w2p, h2);

  att2_k<<<NN, 64, 0, stream>>>(h2, as2c, ad2c, a_s2, a_d2);
  gath2_k<<<NN, 64, 0, stream>>>(start, deg, csr_src, a_s2, a_d2, h2, b2c, d_out, flags);
}

// Round 5
// 623.095 us; speedup vs baseline: 4.7983x; 1.4552x over previous
//
#include <hip/hip_runtime.h>
#include <hip/hip_bf16.h>

#define NN   40000
#define NE   160000
#define ETOT 200000   // NE + NN self loops
#define FIN  602
#define NH1  8
#define C1   256
#define F1   2048     // NH1*C1
#define C2   42
#define NEG  0.2f
#define NB   157      // ceil(NN/256)
#define KP   608      // FIN padded to mult of 32
#define MP   40064    // NN padded to mult of 128 (313*128)

typedef unsigned short u16;
typedef unsigned int   u32;
typedef __bf16 bf16x8 __attribute__((ext_vector_type(8)));
typedef float  f32x4  __attribute__((ext_vector_type(4)));

__device__ __forceinline__ float bfu(u16 v){ return __uint_as_float(((u32)v) << 16); }
__device__ __forceinline__ float bflo(u32 u){ return __uint_as_float(u << 16); }
__device__ __forceinline__ float bfhi(u32 u){ return __uint_as_float(u & 0xffff0000u); }
__device__ __forceinline__ u16 f2bf(float f){
  u32 u = __float_as_uint(f);
  u32 r = (u + 0x7fffu + ((u >> 16) & 1u)) >> 16;   // RNE
  return (u16)r;
}

// async global->LDS, 16B per lane; LDS dest = wave-uniform base + lane*16
__device__ __forceinline__ void gl_lds16(const u16* g, u16* l) {
  __builtin_amdgcn_global_load_lds(
      (const __attribute__((address_space(1))) u32*)(g),
      (__attribute__((address_space(3))) u32*)(l), 16, 0, 0);
}

// ================= dtype probe =================
__global__ void probe_k(const u32* __restrict__ xw, const int* __restrict__ ei,
                        int* __restrict__ flags) {
  if (threadIdx.x == 0) {
    int zc = 0;
    for (int k = 0; k < 64; ++k) zc += (ei[2*k + 1] == 0) ? 1 : 0;
    flags[0] = (zc == 64) ? 1 : 0;
    int inr = 0;
    for (int k = 0; k < 64; ++k) {
      u32 low = xw[k] & 0xffffu;
      int e = (int)((low >> 7) & 0xff);
      inr += (e >= 100 && e <= 140) ? 1 : 0;
    }
    flags[1] = (inr >= 32) ? 0 : 1;
  }
}

__global__ void cvt_f32_k(const void* __restrict__ src, float* __restrict__ dst, int n,
                          const int* __restrict__ flags) {
  int i = blockIdx.x * 256 + threadIdx.x;
  if (i >= n) return;
  dst[i] = flags[1] ? ((const float*)src)[i] : bfu(((const u16*)src)[i]);
}

// xb[MP][KP] = x as bf16, zero-padded rows/cols
__global__ void xb_k(const void* __restrict__ x, u16* __restrict__ xb,
                     const int* __restrict__ flags) {
  int k = blockIdx.x * 256 + threadIdx.x;
  int row = blockIdx.y;
  if (k >= KP) return;
  u16 v = 0;
  if (row < NN && k < FIN)
    v = flags[1] ? f2bf(((const float*)x)[(size_t)row * FIN + k])
                 : ((const u16*)x)[(size_t)row * FIN + k];
  xb[(size_t)row * KP + k] = v;
}

// W1t[n][k] = W1[k][n], k padded to 608 with zeros. bf16.
__global__ void w1t_k(const void* __restrict__ W1, u16* __restrict__ w1t,
                      const int* __restrict__ flags) {
  int n = blockIdx.x * 256 + threadIdx.x;
  int k = blockIdx.y;
  if (n >= F1) return;
  u16 v = 0;
  if (k < FIN) v = flags[1] ? f2bf(((const float*)W1)[(size_t)k * F1 + n])
                            : ((const u16*)W1)[(size_t)k * F1 + n];
  w1t[(size_t)n * KP + k] = v;
}

// w2t[c][k] = W2[k][c], c padded 42->64 with zeros. bf16.
__global__ void w2t_k(const void* __restrict__ W2, u16* __restrict__ w2t,
                      const int* __restrict__ flags) {
  int i = blockIdx.x * 256 + threadIdx.x;
  if (i >= 64 * F1) return;
  int c = i >> 11, k = i & (F1 - 1);
  u16 v = 0;
  if (c < C2) v = flags[1] ? f2bf(((const float*)W2)[(size_t)k * C2 + c])
                           : ((const u16*)W2)[(size_t)k * C2 + c];
  w2t[i] = v;
}

// ================= CSR build =================
__device__ __forceinline__ void edge_sd(const int* __restrict__ ei, int e, int imode,
                                        int& s, int& d) {
  if (e < NE) {
    if (imode) { s = ei[2*e]; d = ei[2*(NE + e)]; }
    else       { s = ei[e];   d = ei[NE + e];     }
  } else { s = d = e - NE; }
}

__global__ void deg_k(const int* __restrict__ ei, int* __restrict__ deg,
                      const int* __restrict__ flags) {
  int e = blockIdx.x * 256 + threadIdx.x;
  if (e >= ETOT) return;
  int s, d; edge_sd(ei, e, flags[0], s, d);
  atomicAdd(&deg[d], 1);
}

__global__ __launch_bounds__(256) void scan1_k(const int* __restrict__ deg,
                                               int* __restrict__ tmp, int* __restrict__ bsum) {
  __shared__ int s[256];
  int b = blockIdx.x, t = threadIdx.x, i = b * 256 + t;
  int v = (i < NN) ? deg[i] : 0;
  s[t] = v; __syncthreads();
  for (int o = 1; o < 256; o <<= 1) {
    int u = (t >= o) ? s[t - o] : 0;
    __syncthreads(); s[t] += u; __syncthreads();
  }
  if (i < NN) tmp[i] = s[t];
  if (t == 255) bsum[b] = s[255];
}

__global__ __launch_bounds__(256) void scan2_k(int* __restrict__ bsum) {
  __shared__ int s[256];
  int t = threadIdx.x;
  int v = (t < NB) ? bsum[t] : 0;
  s[t] = v; __syncthreads();
  for (int o = 1; o < 256; o <<= 1) {
    int u = (t >= o) ? s[t - o] : 0;
    __syncthreads(); s[t] += u; __syncthreads();
  }
  if (t < NB) bsum[t] = s[t];
}

__global__ void scan3_k(const int* __restrict__ deg, const int* __restrict__ tmp,
                        const int* __restrict__ bsum, int* __restrict__ start, int* __restrict__ cur) {
  int i = blockIdx.x * 256 + threadIdx.x;
  if (i >= NN) return;
  int b = i >> 8;
  int off = b ? bsum[b - 1] : 0;
  int excl = tmp[i] - deg[i] + off;
  start[i] = excl; cur[i] = excl;
}

__global__ void fill_k(const int* __restrict__ ei, int* __restrict__ cur,
                       int* __restrict__ csr_src, int* __restrict__ csr_dst,
                       const int* __restrict__ flags) {
  int e = blockIdx.x * 256 + threadIdx.x;
  if (e >= ETOT) return;
  int s, d; edge_sd(ei, e, flags[0], s, d);
  int pos = atomicAdd(&cur[d], 1);
  csr_src[pos] = s; csr_dst[pos] = d;
}

// ================= GEMM1 path A (m97 structure): h1 = xb @ W1t^T
// 128x128 tile, BK=32, 4 waves 2x2, global_load_lds staging, linear LDS
__global__ __launch_bounds__(256) void gemm1a_k(const u16* __restrict__ xb,
                                                const u16* __restrict__ w1t,
                                                u16* __restrict__ h1) {
  __shared__ u16 As[128 * 32];
  __shared__ u16 Bs[128 * 32];
  const int t = threadIdx.x;
  const int lane = t & 63, wid = t >> 6;
  const int wr = wid >> 1, wc = wid & 1;
  const int m0 = blockIdx.y * 128, n0 = blockIdx.x * 128;
  const int l16 = lane & 15, lk = (lane >> 4) * 8;
  f32x4 acc[4][4];
  #pragma unroll
  for (int i = 0; i < 4; ++i)
    #pragma unroll
    for (int j = 0; j < 4; ++j) acc[i][j] = (f32x4){0.f, 0.f, 0.f, 0.f};

  // staging geometry: chunk cid in [0,512): row = cid>>2, kc = cid&3
  // issue0: cid = t (rows 0..63), issue1: cid = 256+t (rows 64..127)
  const size_t sa0 = (size_t)(m0 + (t >> 2)) * KP + (t & 3) * 8;
  const size_t sa1 = (size_t)(m0 + 64 + (t >> 2)) * KP + (t & 3) * 8;
  const size_t sb0 = (size_t)(n0 + (t >> 2)) * KP + (t & 3) * 8;
  const size_t sb1 = (size_t)(n0 + 64 + (t >> 2)) * KP + (t & 3) * 8;
  u16* la0 = As + (wid << 9);           // wave-uniform LDS bases
  u16* la1 = As + 2048 + (wid << 9);
  u16* lb0 = Bs + (wid << 9);
  u16* lb1 = Bs + 2048 + (wid << 9);

  for (int k0 = 0; k0 < KP; k0 += 32) {
    gl_lds16(xb + sa0 + k0, la0);
    gl_lds16(xb + sa1 + k0, la1);
    gl_lds16(w1t + sb0 + k0, lb0);
    gl_lds16(w1t + sb1 + k0, lb1);
    __syncthreads();   // drains vmcnt before LDS reads
    bf16x8 bfr[4];
    #pragma unroll
    for (int ni = 0; ni < 4; ++ni)
      bfr[ni] = *(const bf16x8*)&Bs[(wc * 64 + ni * 16 + l16) * 32 + lk];
    #pragma unroll
    for (int mi = 0; mi < 4; ++mi) {
      bf16x8 af = *(const bf16x8*)&As[(wr * 64 + mi * 16 + l16) * 32 + lk];
      #pragma unroll
      for (int ni = 0; ni < 4; ++ni)
        acc[mi][ni] = __builtin_amdgcn_mfma_f32_16x16x32_bf16(af, bfr[ni], acc[mi][ni], 0, 0, 0);
    }
    __syncthreads();
  }
  const int lr4 = (lane >> 4) * 4;
  #pragma unroll
  for (int mi = 0; mi < 4; ++mi) {
    #pragma unroll
    for (int r = 0; r < 4; ++r) {
      int row = m0 + wr * 64 + mi * 16 + lr4 + r;
      if (row < NN) {
        #pragma unroll
        for (int ni = 0; ni < 4; ++ni) {
          int col = n0 + wc * 64 + ni * 16 + l16;
          h1[(size_t)row * F1 + col] = f2bf(acc[mi][ni][r]);
        }
      }
    }
  }
}

// ================= GEMM1 path B (fallback, reg-staged, dual-dtype) =================
__global__ __launch_bounds__(256) void gemm1m_k(const void* __restrict__ xv,
                                                const u16* __restrict__ w1t,
                                                u16* __restrict__ h1,
                                                const int* __restrict__ flags) {
  __shared__ u16 As[128][40];
  __shared__ u16 Bs[128][40];
  const int fm = flags[1];
  const int t = threadIdx.x;
  const int lane = t & 63, wid = t >> 6;
  const int wr = wid >> 1, wc = wid & 1;
  const int m0 = blockIdx.y * 128, n0 = blockIdx.x * 128;
  const int l16 = lane & 15, lk = (lane >> 4) * 8;
  f32x4 acc[4][4];
  #pragma unroll
  for (int i = 0; i < 4; ++i)
    #pragma unroll
    for (int j = 0; j < 4; ++j) acc[i][j] = (f32x4){0.f, 0.f, 0.f, 0.f};
  const int arow = t >> 2;
  const int akb  = (t & 3) * 8;
  for (int k0 = 0; k0 < KP; k0 += 32) {
    #pragma unroll
    for (int i = 0; i < 2; ++i) {
      int row = arow + i * 64;
      int rg = m0 + row;
      u32 d0 = 0, d1 = 0, d2 = 0, d3 = 0;
      if (rg < NN) {
        if (k0 + 32 <= FIN) {
          if (fm) {
            const float* xp = (const float*)xv + (size_t)rg * FIN + k0 + akb;
            float2 p0 = *(const float2*)(xp);
            float2 p1 = *(const float2*)(xp + 2);
            float2 p2 = *(const float2*)(xp + 4);
            float2 p3 = *(const float2*)(xp + 6);
            d0 = (u32)f2bf(p0.x) | ((u32)f2bf(p0.y) << 16);
            d1 = (u32)f2bf(p1.x) | ((u32)f2bf(p1.y) << 16);
            d2 = (u32)f2bf(p2.x) | ((u32)f2bf(p2.y) << 16);
            d3 = (u32)f2bf(p3.x) | ((u32)f2bf(p3.y) << 16);
          } else {
            const u16* xp = (const u16*)xv + (size_t)rg * FIN + k0 + akb;
            d0 = *(const u32*)(xp);
            d1 = *(const u32*)(xp + 2);
            d2 = *(const u32*)(xp + 4);
            d3 = *(const u32*)(xp + 6);
          }
        } else {
          u16 e[8];
          #pragma unroll
          for (int q = 0; q < 8; ++q) {
            int k = k0 + akb + q;
            e[q] = 0;
            if (k < FIN)
              e[q] = fm ? f2bf(((const float*)xv)[(size_t)rg * FIN + k])
                        : ((const u16*)xv)[(size_t)rg * FIN + k];
          }
          d0 = (u32)e[0] | ((u32)e[1] << 16);
          d1 = (u32)e[2] | ((u32)e[3] << 16);
          d2 = (u32)e[4] | ((u32)e[5] << 16);
          d3 = (u32)e[6] | ((u32)e[7] << 16);
        }
      }
      *(uint4*)&As[row][akb] = make_uint4(d0, d1, d2, d3);
      const u16* wp = w1t + (size_t)(n0 + row) * KP + k0 + akb;
      *(uint4*)&Bs[row][akb] = *(const uint4*)wp;
    }
    __syncthreads();
    bf16x8 bfr[4];
    #pragma unroll
    for (int ni = 0; ni < 4; ++ni)
      bfr[ni] = *(const bf16x8*)&Bs[wc * 64 + ni * 16 + l16][lk];
    #pragma unroll
    for (int mi = 0; mi < 4; ++mi) {
      bf16x8 af = *(const bf16x8*)&As[wr * 64 + mi * 16 + l16][lk];
      #pragma unroll
      for (int ni = 0; ni < 4; ++ni)
        acc[mi][ni] = __builtin_amdgcn_mfma_f32_16x16x32_bf16(af, bfr[ni], acc[mi][ni], 0, 0, 0);
    }
    __syncthreads();
  }
  const int lr4 = (lane >> 4) * 4;
  #pragma unroll
  for (int mi = 0; mi < 4; ++mi) {
    #pragma unroll
    for (int r = 0; r < 4; ++r) {
      int row = m0 + wr * 64 + mi * 16 + lr4 + r;
      if (row < NN) {
        #pragma unroll
        for (int ni = 0; ni < 4; ++ni) {
          int col = n0 + wc * 64 + ni * 16 + l16;
          h1[(size_t)row * F1 + col] = f2bf(acc[mi][ni][r]);
        }
      }
    }
  }
}

// ================= attention scalars, all 8 heads at once
__global__ __launch_bounds__(256) void att1_k(const u16* __restrict__ h1,
                                              const float* __restrict__ as1c, const float* __restrict__ ad1c,
                                              float* __restrict__ a_s, float* __restrict__ a_d) {
  int n = blockIdx.x, t = threadIdx.x;
  int h = t >> 5, l = t & 31;
  int base = h * C1 + l * 8;
  const u16* hp = h1 + (size_t)n * F1 + base;
  uint4 v = *(const uint4*)hp;
  u32 w[4] = {v.x, v.y, v.z, v.w};
  float ss = 0.f, sd = 0.f;
  #pragma unroll
  for (int p = 0; p < 4; ++p) {
    float e0 = bflo(w[p]), e1 = bfhi(w[p]);
    ss += e0 * as1c[base + 2*p] + e1 * as1c[base + 2*p + 1];
    sd += e0 * ad1c[base + 2*p] + e1 * ad1c[base + 2*p + 1];
  }
  #pragma unroll
  for (int o = 16; o > 0; o >>= 1) {
    ss += __shfl_down(ss, o, 32);
    sd += __shfl_down(sd, o, 32);
  }
  if (l == 0) { a_s[n * NH1 + h] = ss; a_d[n * NH1 + h] = sd; }
}

// per-CSR-position exp scores, all heads: ex1[j][h]
__global__ void ex1_k(const int* __restrict__ csr_src, const int* __restrict__ csr_dst,
                      const float* __restrict__ a_s, const float* __restrict__ a_d,
                      float* __restrict__ ex1) {
  int gid = blockIdx.x * 256 + threadIdx.x;
  if (gid >= ETOT * NH1) return;
  int j = gid >> 3, h = gid & 7;
  float v = a_s[csr_src[j] * NH1 + h] + a_d[csr_dst[j] * NH1 + h];
  v = v > 0.f ? v : NEG * v;
  ex1[gid] = expf(v);
}

// ================= fused: gather(all heads)+bias+ReLU -> LDS -> MFMA @ w2t -> h2
// 16 nodes per block; rowsL XOR-swizzled to kill ds_read_b128 bank conflicts
__global__ __launch_bounds__(256) void gfuse_k(const int* __restrict__ start, const int* __restrict__ deg,
                                               const int* __restrict__ csr_src, const float* __restrict__ ex1,
                                               const u16* __restrict__ h1, const float* __restrict__ b1c,
                                               const u16* __restrict__ w2t, float* __restrict__ h2) {
  __shared__ u16 rowsL[16 * F1];   // 64 KB
  int t = threadIdx.x;
  int nb = blockIdx.x * 16;
  for (int i = 0; i < 16; ++i) {
    int n = nb + i;
    int s0 = start[n], cnt = deg[n];
    float acc[NH1], den[NH1];
    #pragma unroll
    for (int h = 0; h < NH1; ++h) { acc[h] = 0.f; den[h] = 0.f; }
    for (int j = s0; j < s0 + cnt; ++j) {
      int s = csr_src[j];
      const u16* hp = h1 + (size_t)s * F1 + t;
      const float* ep = ex1 + (size_t)j * NH1;
      #pragma unroll
      for (int h = 0; h < NH1; ++h) {
        float e = ep[h];
        den[h] += e;
        acc[h] += e * bfu(hp[h * C1]);
      }
    }
    int sw = (i & 7) << 3;
    #pragma unroll
    for (int h = 0; h < NH1; ++h) {
      float r = acc[h] / (den[h] + 1e-16f) + b1c[h * C1 + t];
      int c = h * C1 + t;
      rowsL[i * F1 + (c ^ sw)] = f2bf(fmaxf(r, 0.f));
    }
  }
  __syncthreads();
  // phase B: C[16 nodes][64 cols] = rowsL @ w2t^T; wave wid owns col tile wid*16
  int lane = t & 63, wid = t >> 6;
  int l16 = lane & 15, lk = (lane >> 4) * 8;
  const u16* wt = w2t + (size_t)(wid * 16 + l16) * F1;
  int sw = (l16 & 7) << 3;
  f32x4 acc2 = (f32x4){0.f, 0.f, 0.f, 0.f};
  for (int k0 = 0; k0 < F1; k0 += 32) {
    int kk = k0 + lk;
    bf16x8 af = *(const bf16x8*)&rowsL[l16 * F1 + (kk ^ sw)];
    bf16x8 bf = *(const bf16x8*)(wt + kk);
    acc2 = __builtin_amdgcn_mfma_f32_16x16x32_bf16(af, bf, acc2, 0, 0, 0);
  }
  int col = wid * 16 + l16;
  if (col < C2) {
    int mb = (lane >> 4) * 4;
    #pragma unroll
    for (int r = 0; r < 4; ++r)
      h2[(size_t)(nb + mb + r) * C2 + col] = acc2[r];
  }
}

// ================= attention scalars layer 2
__global__ __launch_bounds__(64) void att2_k(const float* __restrict__ h2,
                                             const float* __restrict__ as2, const float* __restrict__ ad2,
                                             float* __restrict__ a_s, float* __restrict__ a_d) {
  int n = blockIdx.x, t = threadIdx.x;
  float ss = 0.f, sd = 0.f;
  if (t < C2) {
    float v = h2[(size_t)n * C2 + t];
    ss = v * as2[t];
    sd = v * ad2[t];
  }
  #pragma unroll
  for (int o = 32; o > 0; o >>= 1) {
    ss += __shfl_down(ss, o, 64);
    sd += __shfl_down(sd, o, 64);
  }
  if (t == 0) { a_s[n] = ss; a_d[n] = sd; }
}

// ================= layer-2 gather + bias + log_softmax, dual-format output
__global__ __launch_bounds__(64) void gath2_k(const int* __restrict__ start, const int* __restrict__ deg,
                                              const int* __restrict__ csr_src,
                                              const float* __restrict__ a_s, const float* __restrict__ a_d,
                                              const float* __restrict__ h2, const float* __restrict__ b2,
                                              void* __restrict__ outv, const int* __restrict__ flags) {
  int n = blockIdx.x, t = threadIdx.x;
  int s0 = start[n], cnt = deg[n];
  float ad = a_d[n];
  float acc = 0.f, den = 0.f;
  for (int j = s0; j < s0 + cnt; ++j) {
    int s = csr_src[j];
    float v = a_s[s] + ad;
    v = v > 0.f ? v : NEG * v;
    float e = expf(v);
    den += e;
    if (t < C2) acc += e * h2[(size_t)s * C2 + t];
  }
  float raw = (t < C2) ? acc / (den + 1e-16f) + b2[t] : -1e30f;
  float m = raw;
  #pragma unroll
  for (int o = 32; o > 0; o >>= 1) m = fmaxf(m, __shfl_down(m, o, 64));
  m = __shfl(m, 0, 64);
  float e2 = (t < C2) ? expf(raw - m) : 0.f;
  float ssum = e2;
  #pragma unroll
  for (int o = 32; o > 0; o >>= 1) ssum += __shfl_down(ssum, o, 64);
  ssum = __shfl(ssum, 0, 64);
  if (t < C2) {
    float v = raw - m - logf(ssum);
    if (flags[1]) ((float*)outv)[(size_t)n * C2 + t] = v;
    else          ((u16*) outv)[(size_t)n * C2 + t] = f2bf(v);
  }
}

extern "C" void kernel_launch(void* const* d_in, const int* in_sizes, int n_in,
                              void* d_out, int out_size, void* d_ws, size_t ws_size,
                              hipStream_t stream) {
  const void* x   = d_in[0];
  const int*  ei  = (const int*)d_in[1];
  const void* W1  = d_in[2];
  const void* as1 = d_in[3];
  const void* ad1 = d_in[4];
  const void* b1  = d_in[5];
  const void* W2  = d_in[6];
  const void* as2 = d_in[7];
  const void* ad2 = d_in[8];
  const void* b2  = d_in[9];

  char* ws = (char*)d_ws;
  u16*   h1      = (u16*)  (ws);                  // 163,840,000
  float* ex1     = (float*)(ws + 163840000);      //   6,400,000
  float* h2      = (float*)(ws + 170240000);      //   6,720,000
  float* a_s1    = (float*)(ws + 176960000);      //   1,280,000
  float* a_d1    = (float*)(ws + 178240000);      //   1,280,000
  float* a_s2    = (float*)(ws + 179520000);      //     160,000
  float* a_d2    = (float*)(ws + 179680000);      //     160,000
  int*   deg     = (int*)  (ws + 179840000);      //     160,000
  int*   start   = (int*)  (ws + 180000000);      //     160,000
  int*   cur     = (int*)  (ws + 180160000);      //     160,000
  int*   tmp     = (int*)  (ws + 180320000);      //     160,000
  int*   csr_src = (int*)  (ws + 180480000);      //     800,000
  int*   csr_dst = (int*)  (ws + 181280000);      //     800,000
  int*   bsum    = (int*)  (ws + 182080000);      //       1,024
  u16*   w1t     = (u16*)  (ws + 182081024);      //   2,490,368
  u16*   w2t     = (u16*)  (ws + 184571392);      //     262,144
  float* as1c    = (float*)(ws + 184833536);      //       8,192
  float* ad1c    = (float*)(ws + 184841728);      //       8,192
  float* b1c     = (float*)(ws + 184849920);      //       8,192
  float* as2c    = (float*)(ws + 184858112);      //         256
  float* ad2c    = (float*)(ws + 184858368);      //         256
  float* b2c     = (float*)(ws + 184858624);      //         256
  int*   flags   = (int*)  (ws + 184858880);      //         256
  const size_t TOTAL_BASE = 184859136;
  u16*   xb      = (u16*)  (ws + TOTAL_BASE);     //  48,717,824 (path A only)
  const size_t TOTAL_A = TOTAL_BASE + (size_t)MP * KP * 2;  // 233,576,960
  if (ws_size < TOTAL_BASE) return;  // diagnostic: zeroed out -> clean absmax fail
  const bool pathA = (ws_size >= TOTAL_A);

  probe_k<<<1, 64, 0, stream>>>((const u32*)x, ei, flags);

  cvt_f32_k<<<(F1 + 255) / 256, 256, 0, stream>>>(as1, as1c, F1, flags);
  cvt_f32_k<<<(F1 + 255) / 256, 256, 0, stream>>>(ad1, ad1c, F1, flags);
  cvt_f32_k<<<(F1 + 255) / 256, 256, 0, stream>>>(b1, b1c, F1, flags);
  cvt_f32_k<<<1, 256, 0, stream>>>(as2, as2c, C2, flags);
  cvt_f32_k<<<1, 256, 0, stream>>>(ad2, ad2c, C2, flags);
  cvt_f32_k<<<1, 256, 0, stream>>>(b2, b2c, C2, flags);
  w1t_k<<<dim3(8, KP), 256, 0, stream>>>(W1, w1t, flags);
  w2t_k<<<(64 * F1 + 255) / 256, 256, 0, stream>>>(W2, w2t, flags);

  hipMemsetAsync(deg, 0, NN * sizeof(int), stream);
  const int EB = (ETOT + 255) / 256;
  deg_k  <<<EB, 256, 0, stream>>>(ei, deg, flags);
  scan1_k<<<NB, 256, 0, stream>>>(deg, tmp, bsum);
  scan2_k<<<1, 256, 0, stream>>>(bsum);
  scan3_k<<<NB, 256, 0, stream>>>(deg, tmp, bsum, start, cur);
  fill_k <<<EB, 256, 0, stream>>>(ei, cur, csr_src, csr_dst, flags);

  if (pathA) {
    xb_k<<<dim3((KP + 255) / 256, MP), 256, 0, stream>>>(x, xb, flags);
    gemm1a_k<<<dim3(16, MP / 128), 256, 0, stream>>>(xb, w1t, h1);
  } else {
    gemm1m_k<<<dim3(16, MP / 128), 256, 0, stream>>>(x, w1t, h1, flags);
  }
  att1_k<<<NN, 256, 0, stream>>>(h1, as1c, ad1c, a_s1, a_d1);
  ex1_k<<<(ETOT * NH1 + 255) / 256, 256, 0, stream>>>(csr_src, csr_dst, a_s1, a_d1, ex1);
  gfuse_k<<<NN / 16, 256, 0, stream>>>(start, deg, csr_src, ex1, h1, b1c, w2t, h2);

  att2_k<<<NN, 64, 0, stream>>>(h2, as2c, ad2c, a_s2, a_d2);
  gath2_k<<<NN, 64, 0, stream>>>(start, deg, csr_src, a_s2, a_d2, h2, b2c, d_out, flags);
}